// Round 5
// baseline (477.274 us; speedup 1.0000x reference)
//
#include <hip/hip_runtime.h>
#include <stdint.h>

#define S_LEN 2048
#define HID   3584
#define NH    28
#define NKV   4
#define HD    128
#define NQKV  4608   // 3584 + 512 + 512
#define GRP   7      // NH / NKV

typedef float  f32x4  __attribute__((ext_vector_type(4)));
typedef __bf16 bf16x8 __attribute__((ext_vector_type(8)));
typedef __bf16 bf16x4 __attribute__((ext_vector_type(4)));

#define GLOAD_LDS16(gp, lp) \
  __builtin_amdgcn_global_load_lds((const __attribute__((address_space(1))) void*)(gp), \
                                   (__attribute__((address_space(3))) void*)(lp), 16, 0, 0)

// ---------------- elementwise: f32 -> bf16 (x8 per thread) ----------------
__global__ void cvt_f32_bf16(const float* __restrict__ src, __bf16* __restrict__ dst, int n8) {
  int i = blockIdx.x * blockDim.x + threadIdx.x;
  if (i >= n8) return;
  const float4 a = *(const float4*)(src + (size_t)i * 8);
  const float4 b = *(const float4*)(src + (size_t)i * 8 + 4);
  bf16x8 o;
  o[0] = (__bf16)a.x; o[1] = (__bf16)a.y; o[2] = (__bf16)a.z; o[3] = (__bf16)a.w;
  o[4] = (__bf16)b.x; o[5] = (__bf16)b.y; o[6] = (__bf16)b.z; o[7] = (__bf16)b.w;
  *(bf16x8*)(dst + (size_t)i * 8) = o;
}

__global__ void concat_bias(const float* __restrict__ qb, const float* __restrict__ kb,
                            const float* __restrict__ vb, float* __restrict__ dst) {
  int i = blockIdx.x * blockDim.x + threadIdx.x;
  if (i >= NQKV) return;
  float v;
  if (i < HID) v = qb[i];
  else if (i < HID + 512) v = kb[i - HID];
  else v = vb[i - HID - 512];
  dst[i] = v;
}

// ---------------- GEMM: C[M][N] = A[M][K] * B[N][K]^T + bias ----------------
#define BM 128
#define BN 128
#define BK 64

template <typename OutT>
__global__ __launch_bounds__(256) void gemm_bt(
    const __bf16* __restrict__ A, const __bf16* __restrict__ B,
    const float* __restrict__ bias, OutT* __restrict__ C,
    int M, int N, int K)
{
  __shared__ __bf16 As[BM * BK];
  __shared__ __bf16 Bs[BN * BK];

  const int t    = threadIdx.x;
  const int lane = t & 63;
  const int w    = t >> 6;
  const int wm   = w >> 1;
  const int wn   = w & 1;
  const int row0 = blockIdx.y * BM;
  const int col0 = blockIdx.x * BN;
  const int lq   = lane & 15;
  const int lg   = lane >> 4;

  const int sr  = lane >> 3;
  const int sch = (lane & 7) ^ (sr & 7);
  const __bf16* aG = A + (size_t)(row0 + w * 32 + sr) * K + sch * 8;
  const __bf16* bG = B + (size_t)(col0 + w * 32 + sr) * K + sch * 8;
  __bf16* asW = As + w * 2048;
  __bf16* bsW = Bs + w * 2048;

  f32x4 acc[4][4];
#pragma unroll
  for (int i = 0; i < 4; ++i)
#pragma unroll
    for (int j = 0; j < 4; ++j) { acc[i][j][0]=0.f; acc[i][j][1]=0.f; acc[i][j][2]=0.f; acc[i][j][3]=0.f; }

  for (int kt = 0; kt < K; kt += BK) {
    __syncthreads();
#pragma unroll
    for (int seg = 0; seg < 4; ++seg) {
      GLOAD_LDS16(aG + (size_t)seg * 8 * K + kt, asW + seg * 512);
      GLOAD_LDS16(bG + (size_t)seg * 8 * K + kt, bsW + seg * 512);
    }
    __syncthreads();

#pragma unroll
    for (int kk = 0; kk < 2; ++kk) {
      const int ch = kk * 4 + lg;
      bf16x8 af[4], bfr[4];
#pragma unroll
      for (int mf = 0; mf < 4; ++mf) {
        int r = wm * 64 + mf * 16 + lq;
        af[mf] = *(const bf16x8*)(As + r * BK + ((ch ^ (r & 7)) * 8));
      }
#pragma unroll
      for (int nf = 0; nf < 4; ++nf) {
        int r = wn * 64 + nf * 16 + lq;
        bfr[nf] = *(const bf16x8*)(Bs + r * BK + ((ch ^ (r & 7)) * 8));
      }
#pragma unroll
      for (int mf = 0; mf < 4; ++mf)
#pragma unroll
        for (int nf = 0; nf < 4; ++nf)
          acc[mf][nf] = __builtin_amdgcn_mfma_f32_16x16x32_bf16(af[mf], bfr[nf], acc[mf][nf], 0, 0, 0);
    }
  }

#pragma unroll
  for (int mf = 0; mf < 4; ++mf) {
#pragma unroll
    for (int nf = 0; nf < 4; ++nf) {
      int col = col0 + wn * 64 + nf * 16 + lq;
      float bv = bias ? bias[col] : 0.0f;
#pragma unroll
      for (int r = 0; r < 4; ++r) {
        int rowg = row0 + wm * 64 + mf * 16 + lg * 4 + r;
        C[(size_t)rowg * N + col] = (OutT)(acc[mf][nf][r] + bv);
      }
    }
  }
}

// ---------------- RoPE on Q/K (bf16 in/out, x8 per thread) ----------------
__global__ void rope_qk(const __bf16* __restrict__ qkv,
                        const float* __restrict__ cosb,
                        const float* __restrict__ sinb,
                        __bf16* __restrict__ Qo, __bf16* __restrict__ Ko)
{
  int i = blockIdx.x * blockDim.x + threadIdx.x;
  if (i >= S_LEN * 512) return;
  const int s   = i >> 9;
  const int col = (i & 511) * 8;
  const int d   = col & 127;
  const int axis = (d < 16) ? 0 : (d < 40) ? 1 : (d < 64) ? 2
                 : (d < 80) ? 0 : (d < 104) ? 1 : 2;

  const bf16x8 xv = *(const bf16x8*)(qkv + (size_t)s * NQKV + col);
  const int pcol  = col + ((d < 64) ? 64 : -64);
  const bf16x8 pv = *(const bf16x8*)(qkv + (size_t)s * NQKV + pcol);
  const float sgn = (d < 64) ? -1.0f : 1.0f;

  const float* cp = cosb + ((size_t)axis * S_LEN + s) * HD + d;
  const float* sp = sinb + ((size_t)axis * S_LEN + s) * HD + d;
  bf16x8 o;
#pragma unroll
  for (int j = 0; j < 8; ++j)
    o[j] = (__bf16)((float)xv[j] * cp[j] + sgn * (float)pv[j] * sp[j]);

  if (col < HID) {
    int h = col >> 7;
    *(bf16x8*)(Qo + ((size_t)h * S_LEN + s) * HD + d) = o;
  } else {
    int kh = (col - HID) >> 7;
    *(bf16x8*)(Ko + ((size_t)kh * S_LEN + s) * HD + d) = o;
  }
}

// ---------------- V transpose ----------------
__global__ __launch_bounds__(256) void v_transpose(const __bf16* __restrict__ qkv,
                                                   __bf16* __restrict__ Vt)
{
  __shared__ __bf16 tile[64][72];
  const int b   = blockIdx.x;
  const int kh  = b >> 6;
  const int s0  = ((b >> 1) & 31) * 64;
  const int d0  = (b & 1) * 64;
  const int t   = threadIdx.x;

#pragma unroll
  for (int p = 0; p < 2; ++p) {
    int sl = p * 32 + (t >> 3);
    int c  = t & 7;
    bf16x8 v = *(const bf16x8*)(qkv + (size_t)(s0 + sl) * NQKV + 4096 + kh * HD + d0 + c * 8);
#pragma unroll
    for (int j = 0; j < 8; ++j) tile[sl][c * 8 + j] = v[j];
  }
  __syncthreads();
#pragma unroll
  for (int p = 0; p < 2; ++p) {
    int idx = p * 256 + t;
    int dl  = idx >> 3;
    int sg  = idx & 7;
    bf16x8 o;
#pragma unroll
    for (int j = 0; j < 8; ++j) o[j] = tile[sg * 8 + j][dl];
    *(bf16x8*)(Vt + ((size_t)kh * HD + d0 + dl) * S_LEN + s0 + sg * 8) = o;
  }
}

// ---------------- Flash attention: swapped-operand, in-register softmax ----------------
// Grid: (S/64, NH) reversed. Block: 256 = 4 waves; wave owns 16 q-rows (q = q0w + lq).
// KVBLK=32. K in LDS (dbuf, gload_lds, 16KB). V^T fragments straight to registers.
// Softmax fully lane-local: S^T[k][q=lq] via mfma(K,Q); 2-shuffle row reduce;
// P redistributed to PV B-frag via 8 __shfl; PV computes O^T (A=V^T rows).
__global__ __launch_bounds__(256, 3) void attn_fwd(
    const __bf16* __restrict__ Q, const __bf16* __restrict__ K,
    const __bf16* __restrict__ Vt, __bf16* __restrict__ O)
{
  __shared__ __bf16 Ks[2 * 32 * HD];   // dbuf: 32 k-rows x 128 d (swizzled), 8KB each

  const int t     = threadIdx.x;
  const int lane  = t & 63;
  const int w     = t >> 6;
  const int qtile = (gridDim.x - 1) - blockIdx.x;
  const int h     = blockIdx.y;
  const int kvh   = h / GRP;
  const int q0w   = qtile * 64 + w * 16;
  const int lq    = lane & 15;
  const int lg    = lane >> 4;

  const int krow_in = lane >> 4;   // 0..3
  const int kch     = lane & 15;
  const __bf16* Kbase = K  + (size_t)kvh * S_LEN * HD;
  const __bf16* Vbase = Vt + (size_t)kvh * HD * S_LEN;

  // Q fragments: lane holds Q[q0w+lq][dd*32 + lg*8 ..]
  bf16x8 qf[4];
  {
    const __bf16* qp = Q + ((size_t)h * S_LEN + q0w + lq) * HD + lg * 8;
#pragma unroll
    for (int dd = 0; dd < 4; ++dd) qf[dd] = *(const bf16x8*)(qp + dd * 32);
  }

  f32x4 of[8];   // O^T frag: d = db*16 + lg*4 + r, q = lq
#pragma unroll
  for (int i = 0; i < 8; ++i) { of[i][0]=0.f; of[i][1]=0.f; of[i][2]=0.f; of[i][3]=0.f; }
  float m_run = -1e30f, l_run = 0.0f;

  const float scale = 0.08838834764831845f;
  const int nkt = qtile * 2 + 2;

  // P-redistribution source lanes (per 4-lane column group sharing lq)
  const int s1 = lq + 16 * ((2 * lg) & 3);
  const int s2 = lq + 16 * ((2 * lg + 1) & 3);
  const bool hisel = (lg >> 1) != 0;   // kb select for this lane's B-frag

#define STAGE_K(ktile, b)                                                        \
  {                                                                              \
    _Pragma("unroll")                                                            \
    for (int j = 0; j < 2; ++j) {                                                \
      int rr = (w * 2 + j) * 4 + krow_in;                                        \
      int sc = kch ^ (rr & 7);                                                   \
      GLOAD_LDS16(Kbase + (size_t)((ktile) * 32 + rr) * HD + sc * 8,             \
                  Ks + (b) * 4096 + (w * 2 + j) * 512);                          \
    }                                                                            \
  }

  STAGE_K(0, 0);
  __syncthreads();

  int cur = 0;
  for (int kt = 0; kt < nkt; ++kt) {
    const bool active = (kt * 32) <= (q0w + 15);   // wave-uniform

    // V^T fragments to registers FIRST (oldest in vmcnt queue): lane holds
    // V^T[db*16+lq][kt*32 + lg*8 ..+7]
    uint4 vraw[8];
    if (active) {
#pragma unroll
      for (int db = 0; db < 8; ++db)
        vraw[db] = *(const uint4*)(Vbase + (size_t)(db * 16 + lq) * S_LEN + kt * 32 + lg * 8);
    }

    if (kt + 1 < nkt) STAGE_K(kt + 1, cur ^ 1);

    if (active) {
      const __bf16* KsC = Ks + cur * 4096;

      // swapped QK^T: S^T[k][q=lq]; k = kb*16 + lg*4 + r (+ kt*32)
      f32x4 sf[2];
      __builtin_amdgcn_s_setprio(1);
#pragma unroll
      for (int kb = 0; kb < 2; ++kb) {
        sf[kb][0]=0.f; sf[kb][1]=0.f; sf[kb][2]=0.f; sf[kb][3]=0.f;
#pragma unroll
        for (int dd = 0; dd < 4; ++dd) {
          int r  = kb * 16 + lq;
          int ch = dd * 4 + lg;
          bf16x8 kf = *(const bf16x8*)(KsC + r * HD + ((ch ^ (r & 7)) * 8));
          sf[kb] = __builtin_amdgcn_mfma_f32_16x16x32_bf16(kf, qf[dd], sf[kb], 0, 0, 0);
        }
      }
      __builtin_amdgcn_s_setprio(0);

      // scale + causal mask (q = q0w + lq, per-lane)
      const int qg = q0w + lq;
      const bool diag = (kt * 32 + 31) > q0w;
      float pmax = -1e30f;
#pragma unroll
      for (int kb = 0; kb < 2; ++kb) {
#pragma unroll
        for (int r = 0; r < 4; ++r) {
          float v = sf[kb][r] * scale;
          if (diag) {
            int kg = kt * 32 + kb * 16 + lg * 4 + r;
            if (kg > qg) v = -1e30f;
          }
          sf[kb][r] = v;
          pmax = fmaxf(pmax, v);
        }
      }
      // row reduce across the 4 lanes sharing lq
      pmax = fmaxf(pmax, __shfl_xor(pmax, 16));
      pmax = fmaxf(pmax, __shfl_xor(pmax, 32));

      const float mn = fmaxf(m_run, pmax);
      const float escale = __expf(m_run - mn);
      m_run = mn;

      float psum = 0.0f;
      uint32_t pk[2][2];   // packed bf16 pairs: pk[kb][i] = (p[2i+1]<<16)|p[2i]
#pragma unroll
      for (int kb = 0; kb < 2; ++kb) {
        float p0 = __expf(sf[kb][0] - mn);
        float p1 = __expf(sf[kb][1] - mn);
        float p2 = __expf(sf[kb][2] - mn);
        float p3 = __expf(sf[kb][3] - mn);
        psum += (p0 + p1) + (p2 + p3);
        unsigned short b0 = __builtin_bit_cast(unsigned short, (__bf16)p0);
        unsigned short b1 = __builtin_bit_cast(unsigned short, (__bf16)p1);
        unsigned short b2 = __builtin_bit_cast(unsigned short, (__bf16)p2);
        unsigned short b3 = __builtin_bit_cast(unsigned short, (__bf16)p3);
        pk[kb][0] = (uint32_t)b0 | ((uint32_t)b1 << 16);
        pk[kb][1] = (uint32_t)b2 | ((uint32_t)b3 << 16);
      }
      psum += __shfl_xor(psum, 16);
      psum += __shfl_xor(psum, 32);
      l_run = l_run * escale + psum;

#pragma unroll
      for (int db = 0; db < 8; ++db) {
        of[db][0] *= escale; of[db][1] *= escale;
        of[db][2] *= escale; of[db][3] *= escale;
      }

      // Build PV B-frag: lane needs P[q=lq][k = lg*8 + j], j=0..7 as bf16x8.
      // j0..3 from lane s1 (regs pk[kb][0..1]), j4..7 from lane s2.
      uint32_t a0 = __shfl((int)pk[0][0], s1), a1 = __shfl((int)pk[0][1], s1);
      uint32_t b0 = __shfl((int)pk[1][0], s1), b1 = __shfl((int)pk[1][1], s1);
      uint32_t c0 = __shfl((int)pk[0][0], s2), c1 = __shfl((int)pk[0][1], s2);
      uint32_t d0 = __shfl((int)pk[1][0], s2), d1 = __shfl((int)pk[1][1], s2);
      uint4 pu;
      pu.x = hisel ? b0 : a0;
      pu.y = hisel ? b1 : a1;
      pu.z = hisel ? d0 : c0;
      pu.w = hisel ? d1 : c1;
      bf16x8 pfrag = __builtin_bit_cast(bf16x8, pu);

      // PV (swapped): of[db] += V^T_rows x P  -> O^T[d][q=lq]
      __builtin_amdgcn_s_setprio(1);
#pragma unroll
      for (int db = 0; db < 8; ++db) {
        bf16x8 vf = __builtin_bit_cast(bf16x8, vraw[db]);
        of[db] = __builtin_amdgcn_mfma_f32_16x16x32_bf16(vf, pfrag, of[db], 0, 0, 0);
      }
      __builtin_amdgcn_s_setprio(0);
    }

    __syncthreads();   // protects K dbuf; drains prefetch vmcnt
    cur ^= 1;
  }
#undef STAGE_K

  // epilogue: O[q0w+lq][h*128 + db*16 + lg*4 + r] = of[db][r] / l
  const float rl = 1.0f / l_run;
  __bf16* op = O + (size_t)(q0w + lq) * HID + h * HD + lg * 4;
#pragma unroll
  for (int db = 0; db < 8; ++db) {
    bf16x4 o4;
    o4[0] = (__bf16)(of[db][0] * rl);
    o4[1] = (__bf16)(of[db][1] * rl);
    o4[2] = (__bf16)(of[db][2] * rl);
    o4[3] = (__bf16)(of[db][3] * rl);
    *(bf16x4*)(op + db * 16) = o4;
  }
}

// ---------------- launch ----------------
extern "C" void kernel_launch(void* const* d_in, const int* in_sizes, int n_in,
                              void* d_out, int out_size, void* d_ws, size_t ws_size,
                              hipStream_t stream) {
  const float* hidden = (const float*)d_in[0];
  const float* cosb   = (const float*)d_in[1];
  const float* sinb   = (const float*)d_in[2];
  const float* q_w = (const float*)d_in[4];
  const float* q_b = (const float*)d_in[5];
  const float* k_w = (const float*)d_in[6];
  const float* k_b = (const float*)d_in[7];
  const float* v_w = (const float*)d_in[8];
  const float* v_b = (const float*)d_in[9];
  const float* o_w = (const float*)d_in[10];
  float* out = (float*)d_out;

  char* ws = (char*)d_ws;
  size_t off = 0;
  auto alloc = [&](size_t bytes) {
    off = (off + 255) & ~(size_t)255;
    void* p = ws + off;
    off += bytes;
    return p;
  };

  __bf16* hid_bf  = (__bf16*)alloc((size_t)S_LEN * HID * 2);
  __bf16* Wqkv    = (__bf16*)alloc((size_t)NQKV * HID * 2);
  float*  bias    = (float*) alloc((size_t)NQKV * 4);
  __bf16* qkv_bf  = (__bf16*)alloc((size_t)S_LEN * NQKV * 2);
  __bf16* Qb      = (__bf16*)alloc((size_t)NH * S_LEN * HD * 2);
  __bf16* Kb      = (__bf16*)alloc((size_t)NKV * S_LEN * HD * 2);
  __bf16* Vtb     = (__bf16*)alloc((size_t)NKV * HD * S_LEN * 2);
  __bf16* attn_o  = (__bf16*)alloc((size_t)S_LEN * HID * 2);
  __bf16* ow_bf   = (__bf16*)alloc((size_t)HID * HID * 2);

  const int TB = 256;
  auto cdiv = [](int a, int b) { return (a + b - 1) / b; };

  int n;
  n = S_LEN * HID;  cvt_f32_bf16<<<cdiv(n / 8, TB), TB, 0, stream>>>(hidden, hid_bf, n / 8);
  n = HID * HID;    cvt_f32_bf16<<<cdiv(n / 8, TB), TB, 0, stream>>>(q_w, Wqkv, n / 8);
  n = 512 * HID;    cvt_f32_bf16<<<cdiv(n / 8, TB), TB, 0, stream>>>(k_w, Wqkv + (size_t)HID * HID, n / 8);
  n = 512 * HID;    cvt_f32_bf16<<<cdiv(n / 8, TB), TB, 0, stream>>>(v_w, Wqkv + (size_t)(HID + 512) * HID, n / 8);
  n = HID * HID;    cvt_f32_bf16<<<cdiv(n / 8, TB), TB, 0, stream>>>(o_w, ow_bf, n / 8);
  concat_bias<<<cdiv(NQKV, TB), TB, 0, stream>>>(q_b, k_b, v_b, bias);

  // QKV projection (bf16 out, bias fused)
  {
    dim3 grid(NQKV / BN, S_LEN / BM);
    gemm_bt<__bf16><<<grid, TB, 0, stream>>>(hid_bf, Wqkv, bias, qkv_bf, S_LEN, NQKV, HID);
  }

  // RoPE (Q,K) + V transpose
  n = S_LEN * 512;
  rope_qk<<<cdiv(n, TB), TB, 0, stream>>>(qkv_bf, cosb, sinb, Qb, Kb);
  v_transpose<<<NKV * 32 * 2, TB, 0, stream>>>(qkv_bf, Vtb);

  // flash attention: 64 q-rows per block, 4 waves, in-register softmax
  {
    dim3 grid(S_LEN / 64, NH);
    attn_fwd<<<grid, TB, 0, stream>>>(Qb, Kb, Vtb, attn_o);
  }

  // output projection (f32 out)
  {
    dim3 grid(HID / BN, S_LEN / BM);
    gemm_bt<float><<<grid, TB, 0, stream>>>(attn_o, ow_bf, nullptr, out, S_LEN, HID, HID);
  }
}

// Round 6
// 330.996 us; speedup vs baseline: 1.4419x; 1.4419x over previous
//
#include <hip/hip_runtime.h>
#include <stdint.h>

#define S_LEN 2048
#define HID   3584
#define NH    28
#define NKV   4
#define HD    128
#define NQKV  4608   // 3584 + 512 + 512
#define GRP   7      // NH / NKV

typedef float  f32x4  __attribute__((ext_vector_type(4)));
typedef __bf16 bf16x8 __attribute__((ext_vector_type(8)));
typedef __bf16 bf16x4 __attribute__((ext_vector_type(4)));

#define GLOAD_LDS16(gp, lp) \
  __builtin_amdgcn_global_load_lds((const __attribute__((address_space(1))) void*)(gp), \
                                   (__attribute__((address_space(3))) void*)(lp), 16, 0, 0)

// ---------------- elementwise: f32 -> bf16 (x8 per thread) ----------------
__global__ void cvt_f32_bf16(const float* __restrict__ src, __bf16* __restrict__ dst, int n8) {
  int i = blockIdx.x * blockDim.x + threadIdx.x;
  if (i >= n8) return;
  const float4 a = *(const float4*)(src + (size_t)i * 8);
  const float4 b = *(const float4*)(src + (size_t)i * 8 + 4);
  bf16x8 o;
  o[0] = (__bf16)a.x; o[1] = (__bf16)a.y; o[2] = (__bf16)a.z; o[3] = (__bf16)a.w;
  o[4] = (__bf16)b.x; o[5] = (__bf16)b.y; o[6] = (__bf16)b.z; o[7] = (__bf16)b.w;
  *(bf16x8*)(dst + (size_t)i * 8) = o;
}

__global__ void concat_bias(const float* __restrict__ qb, const float* __restrict__ kb,
                            const float* __restrict__ vb, float* __restrict__ dst) {
  int i = blockIdx.x * blockDim.x + threadIdx.x;
  if (i >= NQKV) return;
  float v;
  if (i < HID) v = qb[i];
  else if (i < HID + 512) v = kb[i - HID];
  else v = vb[i - HID - 512];
  dst[i] = v;
}

// ---------------- GEMM: C[M][N] = A[M][K] * B[N][K]^T + bias ----------------
#define BM 128
#define BN 128
#define BK 64

template <typename OutT>
__global__ __launch_bounds__(256) void gemm_bt(
    const __bf16* __restrict__ A, const __bf16* __restrict__ B,
    const float* __restrict__ bias, OutT* __restrict__ C,
    int M, int N, int K)
{
  __shared__ __bf16 As[BM * BK];
  __shared__ __bf16 Bs[BN * BK];

  const int t    = threadIdx.x;
  const int lane = t & 63;
  const int w    = t >> 6;
  const int wm   = w >> 1;
  const int wn   = w & 1;
  const int row0 = blockIdx.y * BM;
  const int col0 = blockIdx.x * BN;
  const int lq   = lane & 15;
  const int lg   = lane >> 4;

  const int sr  = lane >> 3;
  const int sch = (lane & 7) ^ (sr & 7);
  const __bf16* aG = A + (size_t)(row0 + w * 32 + sr) * K + sch * 8;
  const __bf16* bG = B + (size_t)(col0 + w * 32 + sr) * K + sch * 8;
  __bf16* asW = As + w * 2048;
  __bf16* bsW = Bs + w * 2048;

  f32x4 acc[4][4];
#pragma unroll
  for (int i = 0; i < 4; ++i)
#pragma unroll
    for (int j = 0; j < 4; ++j) { acc[i][j][0]=0.f; acc[i][j][1]=0.f; acc[i][j][2]=0.f; acc[i][j][3]=0.f; }

  for (int kt = 0; kt < K; kt += BK) {
    __syncthreads();
#pragma unroll
    for (int seg = 0; seg < 4; ++seg) {
      GLOAD_LDS16(aG + (size_t)seg * 8 * K + kt, asW + seg * 512);
      GLOAD_LDS16(bG + (size_t)seg * 8 * K + kt, bsW + seg * 512);
    }
    __syncthreads();

#pragma unroll
    for (int kk = 0; kk < 2; ++kk) {
      const int ch = kk * 4 + lg;
      bf16x8 af[4], bfr[4];
#pragma unroll
      for (int mf = 0; mf < 4; ++mf) {
        int r = wm * 64 + mf * 16 + lq;
        af[mf] = *(const bf16x8*)(As + r * BK + ((ch ^ (r & 7)) * 8));
      }
#pragma unroll
      for (int nf = 0; nf < 4; ++nf) {
        int r = wn * 64 + nf * 16 + lq;
        bfr[nf] = *(const bf16x8*)(Bs + r * BK + ((ch ^ (r & 7)) * 8));
      }
#pragma unroll
      for (int mf = 0; mf < 4; ++mf)
#pragma unroll
        for (int nf = 0; nf < 4; ++nf)
          acc[mf][nf] = __builtin_amdgcn_mfma_f32_16x16x32_bf16(af[mf], bfr[nf], acc[mf][nf], 0, 0, 0);
    }
  }

#pragma unroll
  for (int mf = 0; mf < 4; ++mf) {
#pragma unroll
    for (int nf = 0; nf < 4; ++nf) {
      int col = col0 + wn * 64 + nf * 16 + lq;
      float bv = bias ? bias[col] : 0.0f;
#pragma unroll
      for (int r = 0; r < 4; ++r) {
        int rowg = row0 + wm * 64 + mf * 16 + lg * 4 + r;
        C[(size_t)rowg * N + col] = (OutT)(acc[mf][nf][r] + bv);
      }
    }
  }
}

// ---------------- RoPE on Q/K (bf16 in/out, x8 per thread) ----------------
__global__ void rope_qk(const __bf16* __restrict__ qkv,
                        const float* __restrict__ cosb,
                        const float* __restrict__ sinb,
                        __bf16* __restrict__ Qo, __bf16* __restrict__ Ko)
{
  int i = blockIdx.x * blockDim.x + threadIdx.x;
  if (i >= S_LEN * 512) return;
  const int s   = i >> 9;
  const int col = (i & 511) * 8;
  const int d   = col & 127;
  const int axis = (d < 16) ? 0 : (d < 40) ? 1 : (d < 64) ? 2
                 : (d < 80) ? 0 : (d < 104) ? 1 : 2;

  const bf16x8 xv = *(const bf16x8*)(qkv + (size_t)s * NQKV + col);
  const int pcol  = col + ((d < 64) ? 64 : -64);
  const bf16x8 pv = *(const bf16x8*)(qkv + (size_t)s * NQKV + pcol);
  const float sgn = (d < 64) ? -1.0f : 1.0f;

  const float* cp = cosb + ((size_t)axis * S_LEN + s) * HD + d;
  const float* sp = sinb + ((size_t)axis * S_LEN + s) * HD + d;
  bf16x8 o;
#pragma unroll
  for (int j = 0; j < 8; ++j)
    o[j] = (__bf16)((float)xv[j] * cp[j] + sgn * (float)pv[j] * sp[j]);

  if (col < HID) {
    int h = col >> 7;
    *(bf16x8*)(Qo + ((size_t)h * S_LEN + s) * HD + d) = o;
  } else {
    int kh = (col - HID) >> 7;
    *(bf16x8*)(Ko + ((size_t)kh * S_LEN + s) * HD + d) = o;
  }
}

// ---------------- V transpose ----------------
__global__ __launch_bounds__(256) void v_transpose(const __bf16* __restrict__ qkv,
                                                   __bf16* __restrict__ Vt)
{
  __shared__ __bf16 tile[64][72];
  const int b   = blockIdx.x;
  const int kh  = b >> 6;
  const int s0  = ((b >> 1) & 31) * 64;
  const int d0  = (b & 1) * 64;
  const int t   = threadIdx.x;

#pragma unroll
  for (int p = 0; p < 2; ++p) {
    int sl = p * 32 + (t >> 3);
    int c  = t & 7;
    bf16x8 v = *(const bf16x8*)(qkv + (size_t)(s0 + sl) * NQKV + 4096 + kh * HD + d0 + c * 8);
#pragma unroll
    for (int j = 0; j < 8; ++j) tile[sl][c * 8 + j] = v[j];
  }
  __syncthreads();
#pragma unroll
  for (int p = 0; p < 2; ++p) {
    int idx = p * 256 + t;
    int dl  = idx >> 3;
    int sg  = idx & 7;
    bf16x8 o;
#pragma unroll
    for (int j = 0; j < 8; ++j) o[j] = tile[sg * 8 + j][dl];
    *(bf16x8*)(Vt + ((size_t)kh * HD + d0 + dl) * S_LEN + s0 + sg * 8) = o;
  }
}

// ---------------- Flash attention v3: swapped softmax + LDS K/V, KVBLK=64 ----------------
// Grid: (S/128, NH), qtile reversed. Block 256 = 4 waves; wave owns 32 q-rows
// (2 fragment-cols of 16). K and V^T double-buffered in LDS via global_load_lds
// (pre-swizzled source). Softmax lane-local (S^T[k][q=lq]); P redistributed to
// PV B-frags via shuffles; PV outputs O^T. One barrier per KV-64 iteration.
__global__ __launch_bounds__(256, 2) void attn_fwd(
    const __bf16* __restrict__ Q, const __bf16* __restrict__ K,
    const __bf16* __restrict__ Vt, __bf16* __restrict__ O)
{
  __shared__ __bf16 Ks[2][64 * HD];   // 16KB per buf: 64 k-rows x 256B (4-bit XOR swz)
  __shared__ __bf16 Vs[2][HD * 64];   // 16KB per buf: 128 d-rows x 128B (3-bit XOR swz)

  const int t     = threadIdx.x;
  const int lane  = t & 63;
  const int w     = t >> 6;
  const int qtile = (gridDim.x - 1) - blockIdx.x;
  const int h     = blockIdx.y;
  const int kvh   = h / GRP;
  const int q0w   = qtile * 128 + w * 32;
  const int lq    = lane & 15;
  const int lg    = lane >> 4;

  const int krow_in = lane >> 4;   // 0..3
  const int kch     = lane & 15;
  const int vrow_in = lane >> 3;   // 0..7
  const int vch     = lane & 7;
  const __bf16* Kbase = K  + (size_t)kvh * S_LEN * HD;
  const __bf16* Vbase = Vt + (size_t)kvh * HD * S_LEN;

  // Q frags (B-operand of swapped QK^T): lane holds Q[q0w+qi*16+lq][dd*32+lg*8..]
  bf16x8 qf[2][4];
#pragma unroll
  for (int qi = 0; qi < 2; ++qi) {
    const __bf16* qp = Q + ((size_t)h * S_LEN + q0w + qi * 16 + lq) * HD + lg * 8;
#pragma unroll
    for (int dd = 0; dd < 4; ++dd) qf[qi][dd] = *(const bf16x8*)(qp + dd * 32);
  }

  f32x4 of[8][2];   // O^T: d = db*16 + lg*4 + r, q = qi*16 + lq
#pragma unroll
  for (int i = 0; i < 8; ++i)
#pragma unroll
    for (int qi = 0; qi < 2; ++qi) { of[i][qi][0]=0.f; of[i][qi][1]=0.f; of[i][qi][2]=0.f; of[i][qi][3]=0.f; }
  float m_run[2] = {-1e30f, -1e30f}, l_run[2] = {0.0f, 0.0f};

  const float scale = 0.08838834764831845f;
  const int nkt = 2 * qtile + 2;

  // P redistribution lanes (same 4-lane column group sharing q=lq)
  const int srcA = lq + 16 * ((2 * lg) & 3);
  const int srcB = lq + 16 * ((2 * lg + 1) & 3);
  const bool hisel = (lg >> 1) != 0;

#define STAGE_KV(ktile, b)                                                       \
  {                                                                              \
    _Pragma("unroll")                                                            \
    for (int j = 0; j < 4; ++j) {                                                \
      int rr = w * 16 + j * 4 + krow_in;                                         \
      int sc = kch ^ (rr & 15);                                                  \
      GLOAD_LDS16(Kbase + (size_t)((ktile) * 64 + rr) * HD + sc * 8,             \
                  &Ks[b][(w * 16 + j * 4) * HD]);                                \
    }                                                                            \
    _Pragma("unroll")                                                            \
    for (int j = 0; j < 4; ++j) {                                                \
      int rr = w * 32 + j * 8 + vrow_in;                                         \
      int sc = vch ^ (rr & 7);                                                   \
      GLOAD_LDS16(Vbase + (size_t)rr * S_LEN + (ktile) * 64 + sc * 8,            \
                  &Vs[b][(w * 32 + j * 8) * 64]);                                \
    }                                                                            \
  }

  STAGE_KV(0, 0);
  __syncthreads();

  int cur = 0;
  for (int kt = 0; kt < nkt; ++kt) {
    if (kt + 1 < nkt) STAGE_KV(kt + 1, cur ^ 1);

    const bool active = (kt * 64) <= (q0w + 31);   // wave-uniform
    if (active) {
      const __bf16* KsC = &Ks[cur][0];
      const __bf16* VsC = &Vs[cur][0];

      // swapped QK^T: S^T[k][q]; k = kb*16 + lg*4 + r, q = qi*16 + lq
      f32x4 sf[4][2];
      __builtin_amdgcn_s_setprio(1);
#pragma unroll
      for (int kb = 0; kb < 4; ++kb) {
#pragma unroll
        for (int qi = 0; qi < 2; ++qi) { sf[kb][qi][0]=0.f; sf[kb][qi][1]=0.f; sf[kb][qi][2]=0.f; sf[kb][qi][3]=0.f; }
#pragma unroll
        for (int dd = 0; dd < 4; ++dd) {
          int r  = kb * 16 + lq;
          int ch = dd * 4 + lg;
          bf16x8 kf = *(const bf16x8*)(KsC + r * HD + ((ch ^ (r & 15)) * 8));
#pragma unroll
          for (int qi = 0; qi < 2; ++qi)
            sf[kb][qi] = __builtin_amdgcn_mfma_f32_16x16x32_bf16(kf, qf[qi][dd], sf[kb][qi], 0, 0, 0);
        }
      }
      __builtin_amdgcn_s_setprio(0);

      const bool diag = (kt * 64 + 63) > q0w;
      float esc[2];
      uint32_t pk[2][4][2];   // [qi][kb][pair]
#pragma unroll
      for (int qi = 0; qi < 2; ++qi) {
        const int qg = q0w + qi * 16 + lq;
        float pmax = -1e30f;
#pragma unroll
        for (int kb = 0; kb < 4; ++kb) {
#pragma unroll
          for (int r = 0; r < 4; ++r) {
            float v = sf[kb][qi][r] * scale;
            if (diag) {
              int kg = kt * 64 + kb * 16 + lg * 4 + r;
              if (kg > qg) v = -1e30f;
            }
            sf[kb][qi][r] = v;
            pmax = fmaxf(pmax, v);
          }
        }
        pmax = fmaxf(pmax, __shfl_xor(pmax, 16));
        pmax = fmaxf(pmax, __shfl_xor(pmax, 32));

        const float mn = fmaxf(m_run[qi], pmax);
        esc[qi] = __expf(m_run[qi] - mn);
        m_run[qi] = mn;

        float psum = 0.0f;
#pragma unroll
        for (int kb = 0; kb < 4; ++kb) {
          float p0 = __expf(sf[kb][qi][0] - mn);
          float p1 = __expf(sf[kb][qi][1] - mn);
          float p2 = __expf(sf[kb][qi][2] - mn);
          float p3 = __expf(sf[kb][qi][3] - mn);
          psum += (p0 + p1) + (p2 + p3);
          unsigned short b0 = __builtin_bit_cast(unsigned short, (__bf16)p0);
          unsigned short b1 = __builtin_bit_cast(unsigned short, (__bf16)p1);
          unsigned short b2 = __builtin_bit_cast(unsigned short, (__bf16)p2);
          unsigned short b3 = __builtin_bit_cast(unsigned short, (__bf16)p3);
          pk[qi][kb][0] = (uint32_t)b0 | ((uint32_t)b1 << 16);
          pk[qi][kb][1] = (uint32_t)b2 | ((uint32_t)b3 << 16);
        }
        psum += __shfl_xor(psum, 16);
        psum += __shfl_xor(psum, 32);
        l_run[qi] = l_run[qi] * esc[qi] + psum;

#pragma unroll
        for (int db = 0; db < 8; ++db) {
          of[db][qi][0] *= esc[qi]; of[db][qi][1] *= esc[qi];
          of[db][qi][2] *= esc[qi]; of[db][qi][3] *= esc[qi];
        }
      }

      // PV (swapped): of[db][qi] += V^T_rows x P[qi]; k split in two 32-halves
      __builtin_amdgcn_s_setprio(1);
#pragma unroll
      for (int kc = 0; kc < 2; ++kc) {
        bf16x8 pfrag[2];
#pragma unroll
        for (int qi = 0; qi < 2; ++qi) {
          uint32_t a0 = __shfl((int)pk[qi][kc * 2][0],     srcA);
          uint32_t a1 = __shfl((int)pk[qi][kc * 2][1],     srcA);
          uint32_t b0 = __shfl((int)pk[qi][kc * 2 + 1][0], srcA);
          uint32_t b1 = __shfl((int)pk[qi][kc * 2 + 1][1], srcA);
          uint32_t c0 = __shfl((int)pk[qi][kc * 2][0],     srcB);
          uint32_t c1 = __shfl((int)pk[qi][kc * 2][1],     srcB);
          uint32_t d0 = __shfl((int)pk[qi][kc * 2 + 1][0], srcB);
          uint32_t d1 = __shfl((int)pk[qi][kc * 2 + 1][1], srcB);
          uint4 pu;
          pu.x = hisel ? b0 : a0;
          pu.y = hisel ? b1 : a1;
          pu.z = hisel ? d0 : c0;
          pu.w = hisel ? d1 : c1;
          pfrag[qi] = __builtin_bit_cast(bf16x8, pu);
        }
#pragma unroll
        for (int db = 0; db < 8; ++db) {
          int vr = db * 16 + lq;
          int vc = kc * 4 + lg;
          bf16x8 vf = *(const bf16x8*)(VsC + vr * 64 + ((vc ^ (vr & 7)) * 8));
#pragma unroll
          for (int qi = 0; qi < 2; ++qi)
            of[db][qi] = __builtin_amdgcn_mfma_f32_16x16x32_bf16(vf, pfrag[qi], of[db][qi], 0, 0, 0);
        }
      }
      __builtin_amdgcn_s_setprio(0);
    }

    __syncthreads();   // protects dbuf; drains prefetch vmcnt
    cur ^= 1;
  }
#undef STAGE_KV

  // epilogue: O[q][h*128 + d] = of / l ; q = q0w + qi*16 + lq, d = db*16 + lg*4 + r
#pragma unroll
  for (int qi = 0; qi < 2; ++qi) {
    const float rl = 1.0f / l_run[qi];
    __bf16* op = O + (size_t)(q0w + qi * 16 + lq) * HID + h * HD + lg * 4;
#pragma unroll
    for (int db = 0; db < 8; ++db) {
      bf16x4 o4;
      o4[0] = (__bf16)(of[db][qi][0] * rl);
      o4[1] = (__bf16)(of[db][qi][1] * rl);
      o4[2] = (__bf16)(of[db][qi][2] * rl);
      o4[3] = (__bf16)(of[db][qi][3] * rl);
      *(bf16x4*)(op + db * 16) = o4;
    }
  }
}

// ---------------- launch ----------------
extern "C" void kernel_launch(void* const* d_in, const int* in_sizes, int n_in,
                              void* d_out, int out_size, void* d_ws, size_t ws_size,
                              hipStream_t stream) {
  const float* hidden = (const float*)d_in[0];
  const float* cosb   = (const float*)d_in[1];
  const float* sinb   = (const float*)d_in[2];
  const float* q_w = (const float*)d_in[4];
  const float* q_b = (const float*)d_in[5];
  const float* k_w = (const float*)d_in[6];
  const float* k_b = (const float*)d_in[7];
  const float* v_w = (const float*)d_in[8];
  const float* v_b = (const float*)d_in[9];
  const float* o_w = (const float*)d_in[10];
  float* out = (float*)d_out;

  char* ws = (char*)d_ws;
  size_t off = 0;
  auto alloc = [&](size_t bytes) {
    off = (off + 255) & ~(size_t)255;
    void* p = ws + off;
    off += bytes;
    return p;
  };

  __bf16* hid_bf  = (__bf16*)alloc((size_t)S_LEN * HID * 2);
  __bf16* Wqkv    = (__bf16*)alloc((size_t)NQKV * HID * 2);
  float*  bias    = (float*) alloc((size_t)NQKV * 4);
  __bf16* qkv_bf  = (__bf16*)alloc((size_t)S_LEN * NQKV * 2);
  __bf16* Qb      = (__bf16*)alloc((size_t)NH * S_LEN * HD * 2);
  __bf16* Kb      = (__bf16*)alloc((size_t)NKV * S_LEN * HD * 2);
  __bf16* Vtb     = (__bf16*)alloc((size_t)NKV * HD * S_LEN * 2);
  __bf16* attn_o  = (__bf16*)alloc((size_t)S_LEN * HID * 2);
  __bf16* ow_bf   = (__bf16*)alloc((size_t)HID * HID * 2);

  const int TB = 256;
  auto cdiv = [](int a, int b) { return (a + b - 1) / b; };

  int n;
  n = S_LEN * HID;  cvt_f32_bf16<<<cdiv(n / 8, TB), TB, 0, stream>>>(hidden, hid_bf, n / 8);
  n = HID * HID;    cvt_f32_bf16<<<cdiv(n / 8, TB), TB, 0, stream>>>(q_w, Wqkv, n / 8);
  n = 512 * HID;    cvt_f32_bf16<<<cdiv(n / 8, TB), TB, 0, stream>>>(k_w, Wqkv + (size_t)HID * HID, n / 8);
  n = 512 * HID;    cvt_f32_bf16<<<cdiv(n / 8, TB), TB, 0, stream>>>(v_w, Wqkv + (size_t)(HID + 512) * HID, n / 8);
  n = HID * HID;    cvt_f32_bf16<<<cdiv(n / 8, TB), TB, 0, stream>>>(o_w, ow_bf, n / 8);
  concat_bias<<<cdiv(NQKV, TB), TB, 0, stream>>>(q_b, k_b, v_b, bias);

  // QKV projection (bf16 out, bias fused)
  {
    dim3 grid(NQKV / BN, S_LEN / BM);
    gemm_bt<__bf16><<<grid, TB, 0, stream>>>(hid_bf, Wqkv, bias, qkv_bf, S_LEN, NQKV, HID);
  }

  // RoPE (Q,K) + V transpose
  n = S_LEN * 512;
  rope_qk<<<cdiv(n, TB), TB, 0, stream>>>(qkv_bf, cosb, sinb, Qb, Kb);
  v_transpose<<<NKV * 32 * 2, TB, 0, stream>>>(qkv_bf, Vtb);

  // flash attention: 128 q-rows per block, 4 waves x 32q, KVBLK=64
  {
    dim3 grid(S_LEN / 128, NH);
    attn_fwd<<<grid, TB, 0, stream>>>(Qb, Kb, Vtb, attn_o);
  }

  // output projection (f32 out)
  {
    dim3 grid(HID / BN, S_LEN / BM);
    gemm_bt<float><<<grid, TB, 0, stream>>>(attn_o, ow_bf, nullptr, out, S_LEN, HID, HID);
  }
}